// Round 7
// baseline (274.939 us; speedup 1.0000x reference)
//
#include <hip/hip_runtime.h>
#include <hip/hip_cooperative_groups.h>

namespace cg = cooperative_groups;

#define TDIM 4096
#define BDIM 256
#define ADIM 26
#define SDIM 4
#define L_CHUNK 32
#define C_CHUNK 128
#define NEGF -1e30f
#define LOG2E 1.44269504088896340736f

__device__ __forceinline__ float ex2(float x) { return __builtin_amdgcn_exp2f(x); }
__device__ __forceinline__ float lg2(float x) { return __builtin_amdgcn_logf(x); }

__device__ __forceinline__ float l2se2(float a, float b) {
    float mx = fmaxf(a, b), mn = fminf(a, b);
    return mx + lg2(1.f + ex2(mn - mx));
}
__device__ __forceinline__ float l2se3(float a, float b, float c) {
    float mx = fmaxf(fmaxf(a, b), c);
    float md = __builtin_amdgcn_fmed3f(a, b, c);
    float mn = fminf(fminf(a, b), c);
    return mx + lg2(1.f + ex2(md - mx) + ex2(mn - mx));
}
__device__ __forceinline__ float l2se4(float a, float b, float c, float d) {
    float h1 = fmaxf(a, b), l1 = fminf(a, b);
    float h2 = fmaxf(c, d), l2 = fminf(c, d);
    float mx = fmaxf(h1, h2), s2 = fminf(h1, h2);
    return mx + lg2(1.f + ex2(s2 - mx) + ex2(l1 - mx) + ex2(l2 - mx));
}

struct TransA { float A00, A01, A02, A11, A12, A13, A22, A23, A33; };

__device__ __forceinline__ TransA make_transA(const float* __restrict__ trans) {
    TransA A;
    {
        float l0 = trans[0], l1 = trans[1], l2 = trans[2];
        float m = fmaxf(fmaxf(l0, l1), l2);
        float lz = m + __logf(__expf(l0 - m) + __expf(l1 - m) + __expf(l2 - m));
        A.A00 = (l0 - lz) * LOG2E; A.A01 = (l1 - lz) * LOG2E; A.A02 = (l2 - lz) * LOG2E;
    }
    {
        float l1 = trans[5], l2 = trans[6], l3 = trans[7];
        float m = fmaxf(fmaxf(l1, l2), l3);
        float lz = m + __logf(__expf(l1 - m) + __expf(l2 - m) + __expf(l3 - m));
        A.A11 = (l1 - lz) * LOG2E; A.A12 = (l2 - lz) * LOG2E; A.A13 = (l3 - lz) * LOG2E;
    }
    {
        float l2 = trans[10], l3 = trans[11];
        float m = fmaxf(l2, l3);
        float lz = m + __logf(__expf(l2 - m) + __expf(l3 - m));
        A.A22 = (l2 - lz) * LOG2E; A.A23 = (l3 - lz) * LOG2E;
    }
    A.A33 = 0.f;
    return A;
}

// ---------------- Kernel A: log_emit, 2 rows/thread (16B-aligned float4 x loads) ----------------
__global__ __launch_bounds__(256) void le_kernel(const float* __restrict__ x,
                                                 const float* __restrict__ emit,
                                                 float* __restrict__ le) {
    __shared__ float Bmat[SDIM][ADIM];
    int tid = threadIdx.x;
    if (tid < SDIM) {
        float m = -1e30f;
        #pragma unroll
        for (int a = 0; a < ADIM; ++a) m = fmaxf(m, emit[tid * ADIM + a]);
        float tmp[ADIM];
        float z = 0.f;
        #pragma unroll
        for (int a = 0; a < ADIM; ++a) {
            float e = __expf(emit[tid * ADIM + a] - m);
            tmp[a] = e; z += e;
        }
        float inv = 1.f / z;
        #pragma unroll
        for (int a = 0; a < ADIM; ++a) Bmat[tid][a] = tmp[a] * inv;
    }
    __syncthreads();

    int idx = blockIdx.x * 256 + tid;        // 0 .. B*T/2-1
    int b = idx >> 11;                       // T/2 = 2048 pairs per b
    int t = (idx & 2047) << 1;

    const float4* xp = reinterpret_cast<const float4*>(x) + (size_t)idx * 13;  // 208 B, 16B-aligned
    float v[52];
    #pragma unroll
    for (int i = 0; i < 13; ++i) {
        float4 u = xp[i];
        v[i * 4 + 0] = u.x; v[i * 4 + 1] = u.y; v[i * 4 + 2] = u.z; v[i * 4 + 3] = u.w;
    }

    float4 r0, r1;
    {
        float z = 0.f, d0 = 0.f, d1 = 0.f, d2 = 0.f, d3 = 0.f;
        #pragma unroll
        for (int a = 0; a < ADIM; ++a) {
            float e = ex2(v[a] * LOG2E);     // x ~ N(0,1): bounded, no overflow
            z += e;
            d0 = fmaf(e, Bmat[0][a], d0); d1 = fmaf(e, Bmat[1][a], d1);
            d2 = fmaf(e, Bmat[2][a], d2); d3 = fmaf(e, Bmat[3][a], d3);
        }
        float iz = 1.f / z;
        r0.x = lg2(fmaf(d0, iz, 1e-16f)); r0.y = lg2(fmaf(d1, iz, 1e-16f));
        r0.z = lg2(fmaf(d2, iz, 1e-16f)); r0.w = lg2(fmaf(d3, iz, 1e-16f));
    }
    {
        float z = 0.f, d0 = 0.f, d1 = 0.f, d2 = 0.f, d3 = 0.f;
        #pragma unroll
        for (int a = 0; a < ADIM; ++a) {
            float e = ex2(v[26 + a] * LOG2E);
            z += e;
            d0 = fmaf(e, Bmat[0][a], d0); d1 = fmaf(e, Bmat[1][a], d1);
            d2 = fmaf(e, Bmat[2][a], d2); d3 = fmaf(e, Bmat[3][a], d3);
        }
        float iz = 1.f / z;
        r1.x = lg2(fmaf(d0, iz, 1e-16f)); r1.y = lg2(fmaf(d1, iz, 1e-16f));
        r1.z = lg2(fmaf(d2, iz, 1e-16f)); r1.w = lg2(fmaf(d3, iz, 1e-16f));
    }
    float4* lp = reinterpret_cast<float4*>(le);
    lp[(size_t)t * BDIM + b] = r0;
    lp[(size_t)(t + 1) * BDIM + b] = r1;
}

// upper-triangular chunk operator, 10 live entries
struct UT { float m00, m01, m02, m03, m11, m12, m13, m22, m23, m33; };

__device__ __forceinline__ void fstep(UT& M, const TransA& A, float4 e) {
    float n00 = M.m00 + A.A00 + e.x;
    float n01 = l2se2(M.m00 + A.A01, M.m01 + A.A11) + e.y;
    float n02 = l2se3(M.m00 + A.A02, M.m01 + A.A12, M.m02 + A.A22) + e.z;
    float n03 = l2se3(M.m01 + A.A13, M.m02 + A.A23, M.m03) + e.w;
    float n11 = M.m11 + A.A11 + e.y;
    float n12 = l2se2(M.m11 + A.A12, M.m12 + A.A22) + e.z;
    float n13 = l2se3(M.m11 + A.A13, M.m12 + A.A23, M.m13) + e.w;
    float n22 = M.m22 + A.A22 + e.z;
    float n23 = l2se2(M.m22 + A.A23, M.m23) + e.w;
    float n33 = M.m33 + e.w;
    M.m00 = n00; M.m01 = n01; M.m02 = n02; M.m03 = n03;
    M.m11 = n11; M.m12 = n12; M.m13 = n13; M.m22 = n22; M.m23 = n23; M.m33 = n33;
}

#define ASTEP(E) do { \
    float n0_ = a0 + A.A00; \
    float n1_ = l2se2(a0 + A.A01, a1 + A.A11); \
    float n2_ = l2se3(a0 + A.A02, a1 + A.A12, a2 + A.A22); \
    float n3_ = l2se3(a1 + A.A13, a2 + A.A23, a3); \
    a0 = n0_ + (E).x; a1 = n1_ + (E).y; a2 = n2_ + (E).z; a3 = n3_ + (E).w; \
    float mm_ = fmaxf(fmaxf(a0, a1), fmaxf(a2, a3)); \
    a0 -= mm_; a1 -= mm_; a2 -= mm_; a3 -= mm_; \
} while (0)

#define BSTEP(E) do { \
    float f0_ = (E).x + b0, f1_ = (E).y + b1, f2_ = (E).z + b2, f3_ = (E).w + b3; \
    float n0_ = l2se3(A.A00 + f0_, A.A01 + f1_, A.A02 + f2_); \
    float n1_ = l2se3(A.A11 + f1_, A.A12 + f2_, A.A13 + f3_); \
    float n2_ = l2se2(A.A22 + f2_, A.A23 + f3_); \
    float n3_ = f3_; \
    float bm_ = fmaxf(fmaxf(n0_, n1_), fmaxf(n2_, n3_)); \
    b0 = n0_ - bm_; b1 = n1_ - bm_; b2 = n2_ - bm_; b3 = n3_ - bm_; \
} while (0)

#define GEMIT(AV, Q) do { \
    float g0_ = (AV).x + b0, g1_ = (AV).y + b1, g2_ = (AV).z + b2, g3_ = (AV).w + b3; \
    float gm_ = fmaxf(fmaxf(g0_, g1_), fmaxf(g2_, g3_)); \
    float q0_ = ex2(g0_ - gm_), q1_ = ex2(g1_ - gm_); \
    float q2_ = ex2(g2_ - gm_), q3_ = ex2(g3_ - gm_); \
    float inv_ = 1.f / (q0_ + q1_ + q2_ + q3_); \
    q0_ *= inv_; q1_ *= inv_; q2_ *= inv_; q3_ *= inv_; \
    vals[(Q)*5 + 0] = fmaf(q0_, wv[0][0], fmaf(q1_, wv[1][0], fmaf(q2_, wv[2][0], q3_ * wv[3][0]))); \
    vals[(Q)*5 + 1] = fmaf(q0_, wv[0][1], fmaf(q1_, wv[1][1], fmaf(q2_, wv[2][1], q3_ * wv[3][1]))); \
    vals[(Q)*5 + 2] = fmaf(q0_, wv[0][2], fmaf(q1_, wv[1][2], fmaf(q2_, wv[2][2], q3_ * wv[3][2]))); \
    vals[(Q)*5 + 3] = fmaf(q0_, wv[0][3], fmaf(q1_, wv[1][3], fmaf(q2_, wv[2][3], q3_ * wv[3][3]))); \
    vals[(Q)*5 + 4] = fmaf(q0_, wv[0][4], fmaf(q1_, wv[1][4], fmaf(q2_, wv[2][4], q3_ * wv[3][4]))); \
} while (0)

// Cooperative stage of le rows [t0, t0+32] (33 rows x 64 b) into LDS. 128 threads.
__device__ __forceinline__ void stage33(float4* sle, const float4* lebase,
                                        int t0, int bbase, int tid) {
    #pragma unroll
    for (int i = 0; i < 16; ++i) {
        int flat = i * 128 + tid;          // rows 0..31, b fastest
        int row = flat >> 6, bl = flat & 63;
        sle[flat] = lebase[(size_t)(t0 + row) * BDIM + bbase + bl];
    }
    if (tid < 64) {
        int t = t0 + 32; if (t > TDIM - 1) t = TDIM - 1;
        sle[32 * 64 + tid] = lebase[(size_t)t * BDIM + bbase + tid];
    }
    __syncthreads();
}

// ---------------- phase 1: chunk operators (wave0 fwd M, wave1 bwd N), scalar layout ----------------
__device__ __forceinline__ void phase1_impl(const float4* sle, const TransA& A,
                                            int c, int bbase, int tid,
                                            float* Mb, float* Nb) {
    int lane = tid & 63;
    int bb = bbase + lane;
    int t0 = c * L_CHUNK;
    UT M;
    if (tid < 64) {
        float4 lb[L_CHUNK];
        #pragma unroll
        for (int k = 0; k < L_CHUNK; ++k) lb[k] = sle[k * 64 + lane];
        float4 e0 = lb[0];
        if (c == 0) {
            M.m00 = e0.x; M.m11 = e0.y; M.m22 = e0.z; M.m33 = e0.w;
            M.m01 = NEGF; M.m02 = NEGF; M.m03 = NEGF; M.m12 = NEGF; M.m13 = NEGF; M.m23 = NEGF;
        } else {
            M.m00 = A.A00 + e0.x; M.m01 = A.A01 + e0.y; M.m02 = A.A02 + e0.z; M.m03 = NEGF;
            M.m11 = A.A11 + e0.y; M.m12 = A.A12 + e0.z; M.m13 = A.A13 + e0.w;
            M.m22 = A.A22 + e0.z; M.m23 = A.A23 + e0.w; M.m33 = e0.w;
        }
        #pragma unroll
        for (int k = 1; k < L_CHUNK; ++k) fstep(M, A, lb[k]);
        float* o = Mb + (size_t)c * 10 * BDIM + bb;
        o[0 * BDIM] = M.m00; o[1 * BDIM] = M.m01; o[2 * BDIM] = M.m02; o[3 * BDIM] = M.m03;
        o[4 * BDIM] = M.m11; o[5 * BDIM] = M.m12; o[6 * BDIM] = M.m13;
        o[7 * BDIM] = M.m22; o[8 * BDIM] = M.m23; o[9 * BDIM] = M.m33;
    } else {
        float4 lb[L_CHUNK];
        #pragma unroll
        for (int k = 0; k < L_CHUNK; ++k) lb[k] = sle[(k + 1) * 64 + lane];
        M.m00 = 0.f; M.m11 = 0.f; M.m22 = 0.f; M.m33 = 0.f;
        M.m01 = NEGF; M.m02 = NEGF; M.m03 = NEGF; M.m12 = NEGF; M.m13 = NEGF; M.m23 = NEGF;
        int jmax = (c == C_CHUNK - 1) ? (TDIM - 1) : (t0 + L_CHUNK);
        #pragma unroll
        for (int k = 0; k < L_CHUNK; ++k) {
            if (t0 + 1 + k <= jmax) fstep(M, A, lb[k]);
        }
        float* o = Nb + (size_t)c * 10 * BDIM + bb;
        o[0 * BDIM] = M.m00; o[1 * BDIM] = M.m01; o[2 * BDIM] = M.m02; o[3 * BDIM] = M.m03;
        o[4 * BDIM] = M.m11; o[5 * BDIM] = M.m12; o[6 * BDIM] = M.m13;
        o[7 * BDIM] = M.m22; o[8 * BDIM] = M.m23; o[9 * BDIM] = M.m33;
    }
}

// ---------------- phase 2: scalar per-(b,dir) scan over chunk operators, depth-4 ring ----------------
__device__ __forceinline__ void phase2_impl(int gid, const float* Mb, const float* Nb,
                                            const float* initl, float* vin, float* wbuf) {
    int b = gid & 255;
    bool bwd = gid >= 256;
    float v0, v1, v2, v3;
    const float* mp;
    float* op;
    if (!bwd) {
        float i0 = initl[0], i1 = initl[1], i2 = initl[2], i3 = initl[3];
        float m = fmaxf(fmaxf(i0, i1), fmaxf(i2, i3));
        float lz = m + __logf(__expf(i0 - m) + __expf(i1 - m) + __expf(i2 - m) + __expf(i3 - m));
        v0 = (i0 - lz) * LOG2E; v1 = (i1 - lz) * LOG2E; v2 = (i2 - lz) * LOG2E; v3 = (i3 - lz) * LOG2E;
        mp = Mb; op = vin;
    } else {
        v0 = v1 = v2 = v3 = 0.f;
        mp = Nb; op = wbuf;
    }

    float ring[4][10];
    #pragma unroll
    for (int r = 0; r < 4; ++r) {
        int cc = bwd ? (C_CHUNK - 1 - r) : r;
        #pragma unroll
        for (int k = 0; k < 10; ++k) ring[r][k] = mp[((size_t)cc * 10 + k) * BDIM + b];
    }

    for (int s = 0; s < C_CHUNK; s += 4) {
        #pragma unroll
        for (int u = 0; u < 4; ++u) {
            int sc = s + u;
            int c = bwd ? (C_CHUNK - 1 - sc) : sc;
            float cur[10];
            #pragma unroll
            for (int k = 0; k < 10; ++k) cur[k] = ring[u][k];
            int sp = sc + 4; if (sp > C_CHUNK - 1) sp = C_CHUNK - 1;
            int cp = bwd ? (C_CHUNK - 1 - sp) : sp;
            #pragma unroll
            for (int k = 0; k < 10; ++k) ring[u][k] = mp[((size_t)cp * 10 + k) * BDIM + b];

            op[((size_t)c * 4 + 0) * BDIM + b] = v0;   // boundary BEFORE applying op
            op[((size_t)c * 4 + 1) * BDIM + b] = v1;
            op[((size_t)c * 4 + 2) * BDIM + b] = v2;
            op[((size_t)c * 4 + 3) * BDIM + b] = v3;

            float n0, n1, n2, n3;
            if (!bwd) {
                n0 = v0 + cur[0];
                n1 = l2se2(v0 + cur[1], v1 + cur[4]);
                n2 = l2se3(v0 + cur[2], v1 + cur[5], v2 + cur[7]);
                n3 = l2se4(v0 + cur[3], v1 + cur[6], v2 + cur[8], v3 + cur[9]);
            } else {
                n0 = l2se4(cur[0] + v0, cur[1] + v1, cur[2] + v2, cur[3] + v3);
                n1 = l2se3(cur[4] + v1, cur[5] + v2, cur[6] + v3);
                n2 = l2se2(cur[7] + v2, cur[8] + v3);
                n3 = cur[9] + v3;
            }
            float mm = fmaxf(fmaxf(n0, n1), fmaxf(n2, n3));
            v0 = n0 - mm; v1 = n1 - mm; v2 = n2 - mm; v3 = n3 - mm;
        }
    }
}

// ---------------- phase 3: paired fwd/bwd replay + gamma.w emit (sle already staged) ----------------
__device__ __forceinline__ void phase3_impl(const float4* sle, const TransA& A,
                                            int c, int bbase, int tid,
                                            const float* vin, const float* wbuf,
                                            const float* w, float* out,
                                            float4 (*sh_a)[64], float4 (*sh_b)[64]) {
    int lane = tid & 63;
    int bb = bbase + lane;
    int t0 = c * L_CHUNK;

    float wv[SDIM][5];
    #pragma unroll
    for (int s = 0; s < SDIM; ++s)
        #pragma unroll
        for (int o = 0; o < 5; ++o) wv[s][o] = w[s * 5 + o];

    float* op = out + (size_t)bb * TDIM * 5;
    float vals[20];

    if (tid < 64) {
        float4 lb[L_CHUNK];
        #pragma unroll
        for (int k = 0; k < L_CHUNK; ++k) lb[k] = sle[k * 64 + lane];

        float a0 = vin[((size_t)c * 4 + 0) * BDIM + bb];
        float a1 = vin[((size_t)c * 4 + 1) * BDIM + bb];
        float a2 = vin[((size_t)c * 4 + 2) * BDIM + bb];
        float a3 = vin[((size_t)c * 4 + 3) * BDIM + bb];

        if (c == 0) {
            a0 += lb[0].x; a1 += lb[0].y; a2 += lb[0].z; a3 += lb[0].w;
            float mm = fmaxf(fmaxf(a0, a1), fmaxf(a2, a3));
            a0 -= mm; a1 -= mm; a2 -= mm; a3 -= mm;
        } else {
            ASTEP(lb[0]);
        }
        sh_a[0][lane] = make_float4(a0, a1, a2, a3);
        #pragma unroll
        for (int k = 1; k < 16; ++k) {
            ASTEP(lb[k]);
            sh_a[k][lane] = make_float4(a0, a1, a2, a3);
        }
        __syncthreads();
        float b0, b1, b2, b3;
        #pragma unroll
        for (int g = 4; g < 8; ++g) {
            #pragma unroll
            for (int q = 0; q < 4; ++q) {
                int k = g * 4 + q;
                ASTEP(lb[k]);
                float4 bv = sh_b[k - 16][lane];
                b0 = bv.x; b1 = bv.y; b2 = bv.z; b3 = bv.w;
                float4 av = make_float4(a0, a1, a2, a3);
                GEMIT(av, q);
            }
            float4* vo = reinterpret_cast<float4*>(op + (size_t)(t0 + g * 4) * 5);
            vo[0] = make_float4(vals[0],  vals[1],  vals[2],  vals[3]);
            vo[1] = make_float4(vals[4],  vals[5],  vals[6],  vals[7]);
            vo[2] = make_float4(vals[8],  vals[9],  vals[10], vals[11]);
            vo[3] = make_float4(vals[12], vals[13], vals[14], vals[15]);
            vo[4] = make_float4(vals[16], vals[17], vals[18], vals[19]);
        }
    } else {
        float4 eb[L_CHUNK];   // eb[k] = le[t0+1+k]
        #pragma unroll
        for (int k = 0; k < L_CHUNK; ++k) eb[k] = sle[(k + 1) * 64 + lane];

        float b0 = wbuf[((size_t)c * 4 + 0) * BDIM + bb];
        float b1 = wbuf[((size_t)c * 4 + 1) * BDIM + bb];
        float b2 = wbuf[((size_t)c * 4 + 2) * BDIM + bb];
        float b3 = wbuf[((size_t)c * 4 + 3) * BDIM + bb];
        bool lastc = (c == C_CHUNK - 1);

        #pragma unroll
        for (int k = 31; k >= 16; --k) {
            if (!(lastc && k == 31)) BSTEP(eb[k]);   // last chunk: beta[T-1] = 0
            sh_b[k - 16][lane] = make_float4(b0, b1, b2, b3);
        }
        __syncthreads();
        #pragma unroll
        for (int g = 3; g >= 0; --g) {
            #pragma unroll
            for (int q = 3; q >= 0; --q) {
                int k = g * 4 + q;
                BSTEP(eb[k]);
                float4 av = sh_a[k][lane];
                GEMIT(av, q);
            }
            float4* vo = reinterpret_cast<float4*>(op + (size_t)(t0 + g * 4) * 5);
            vo[0] = make_float4(vals[0],  vals[1],  vals[2],  vals[3]);
            vo[1] = make_float4(vals[4],  vals[5],  vals[6],  vals[7]);
            vo[2] = make_float4(vals[8],  vals[9],  vals[10], vals[11]);
            vo[3] = make_float4(vals[12], vals[13], vals[14], vals[15]);
            vo[4] = make_float4(vals[16], vals[17], vals[18], vals[19]);
        }
    }
}

// ---------------- cooperative fused kernel: p1 -> scan -> p2 ----------------
__global__ __launch_bounds__(128, 1) void coop_kernel(const float* le, const float* trans,
                                                      const float* initl, const float* w,
                                                      float* Mb, float* Nb,
                                                      float* vin, float* wbuf, float* out) {
    __shared__ float4 sle[33 * 64];
    __shared__ float4 sh_a[16][64];
    __shared__ float4 sh_b[16][64];
    int tid = threadIdx.x;
    int bid = blockIdx.x;
    int bbase = (bid & 3) * 64;
    int c = bid >> 2;
    TransA A = make_transA(trans);

    stage33(sle, reinterpret_cast<const float4*>(le), c * L_CHUNK, bbase, tid);
    phase1_impl(sle, A, c, bbase, tid, Mb, Nb);

    __threadfence();
    cg::this_grid().sync();

    int gid = bid * 128 + tid;
    if (gid < 512) phase2_impl(gid, Mb, Nb, initl, vin, wbuf);

    __threadfence();
    cg::this_grid().sync();

    phase3_impl(sle, A, c, bbase, tid, vin, wbuf, w, out, sh_a, sh_b);
}

// ---------------- fallback (non-cooperative) kernels ----------------
__global__ __launch_bounds__(128) void p1_fb(const float* le, const float* trans,
                                             float* Mb, float* Nb) {
    __shared__ float4 sle[33 * 64];
    int tid = threadIdx.x;
    int bbase = blockIdx.x * 64;
    int c = blockIdx.y;
    TransA A = make_transA(trans);
    stage33(sle, reinterpret_cast<const float4*>(le), c * L_CHUNK, bbase, tid);
    phase1_impl(sle, A, c, bbase, tid, Mb, Nb);
}

__global__ __launch_bounds__(64) void scan_fb(const float* Mb, const float* Nb,
                                              const float* initl, float* vin, float* wbuf) {
    int gid = blockIdx.x * 64 + threadIdx.x;
    phase2_impl(gid, Mb, Nb, initl, vin, wbuf);
}

__global__ __launch_bounds__(128) void p2_fb(const float* le, const float* vin,
                                             const float* wbuf, const float* trans,
                                             const float* w, float* out) {
    __shared__ float4 sle[33 * 64];
    __shared__ float4 sh_a[16][64];
    __shared__ float4 sh_b[16][64];
    int tid = threadIdx.x;
    int bbase = blockIdx.x * 64;
    int c = blockIdx.y;
    TransA A = make_transA(trans);
    stage33(sle, reinterpret_cast<const float4*>(le), c * L_CHUNK, bbase, tid);
    phase3_impl(sle, A, c, bbase, tid, vin, wbuf, w, out, sh_a, sh_b);
}

extern "C" void kernel_launch(void* const* d_in, const int* in_sizes, int n_in,
                              void* d_out, int out_size, void* d_ws, size_t ws_size,
                              hipStream_t stream) {
    const float* x     = (const float*)d_in[0];
    const float* emit  = (const float*)d_in[1];
    const float* trans = (const float*)d_in[2];
    const float* initl = (const float*)d_in[3];
    const float* w     = (const float*)d_in[4];
    float* out = (float*)d_out;

    const size_t LE_BYTES = (size_t)TDIM * BDIM * SDIM * 4;            // 16 MB
    const size_t MB_BYTES = (size_t)C_CHUNK * 10 * BDIM * 4;           // 1.31 MB
    const size_t VB_BYTES = (size_t)C_CHUNK * 4 * BDIM * 4;            // 512 KB

    char* p = (char*)d_ws;
    float* le   = (float*)p;  p += LE_BYTES;
    float* Mb   = (float*)p;  p += MB_BYTES;
    float* Nb   = (float*)p;  p += MB_BYTES;
    float* vin  = (float*)p;  p += VB_BYTES;
    float* wbuf = (float*)p;

    hipLaunchKernelGGL(le_kernel, dim3(BDIM * TDIM / 512), dim3(256), 0, stream, x, emit, le);

    void* kargs[] = {(void*)&le, (void*)&trans, (void*)&initl, (void*)&w,
                     (void*)&Mb, (void*)&Nb, (void*)&vin, (void*)&wbuf, (void*)&out};
    hipError_t err = hipLaunchCooperativeKernel((const void*)coop_kernel,
                                                dim3(512), dim3(128), kargs, 0, stream);
    if (err != hipSuccess) {
        hipLaunchKernelGGL(p1_fb, dim3(BDIM / 64, C_CHUNK), dim3(128), 0, stream, le, trans, Mb, Nb);
        hipLaunchKernelGGL(scan_fb, dim3(8), dim3(64), 0, stream, Mb, Nb, initl, vin, wbuf);
        hipLaunchKernelGGL(p2_fb, dim3(BDIM / 64, C_CHUNK), dim3(128), 0, stream, le, vin, wbuf, trans, w, out);
    }
}

// Round 8
// 65.215 us; speedup vs baseline: 4.2159x; 4.2159x over previous
//
#include <hip/hip_runtime.h>

#define TDIM 4096
#define BDIM 256
#define ADIM 26
#define SDIM 4
#define NEGF -1e30f
#define LOG2E 1.44269504088896340736f

__device__ __forceinline__ float ex2(float x) { return __builtin_amdgcn_exp2f(x); }
__device__ __forceinline__ float lg2(float x) { return __builtin_amdgcn_logf(x); }

__device__ __forceinline__ float l2se2(float a, float b) {
    float mx = fmaxf(a, b), mn = fminf(a, b);
    return mx + lg2(1.f + ex2(mn - mx));
}
__device__ __forceinline__ float l2se3(float a, float b, float c) {
    float mx = fmaxf(fmaxf(a, b), c);
    float md = __builtin_amdgcn_fmed3f(a, b, c);
    float mn = fminf(fminf(a, b), c);
    return mx + lg2(1.f + ex2(md - mx) + ex2(mn - mx));
}
__device__ __forceinline__ float l2se4(float a, float b, float c, float d) {
    float h1 = fmaxf(a, b), l1 = fminf(a, b);
    float h2 = fmaxf(c, d), l2 = fminf(c, d);
    float mx = fmaxf(h1, h2), s2 = fminf(h1, h2);
    return mx + lg2(1.f + ex2(s2 - mx) + ex2(l1 - mx) + ex2(l2 - mx));
}

struct TransA { float A00, A01, A02, A11, A12, A13, A22, A23, A33; };

__device__ __forceinline__ TransA make_transA(const float* __restrict__ trans) {
    TransA A;
    {
        float l0 = trans[0], l1 = trans[1], l2 = trans[2];
        float m = fmaxf(fmaxf(l0, l1), l2);
        float lz = m + __logf(__expf(l0 - m) + __expf(l1 - m) + __expf(l2 - m));
        A.A00 = (l0 - lz) * LOG2E; A.A01 = (l1 - lz) * LOG2E; A.A02 = (l2 - lz) * LOG2E;
    }
    {
        float l1 = trans[5], l2 = trans[6], l3 = trans[7];
        float m = fmaxf(fmaxf(l1, l2), l3);
        float lz = m + __logf(__expf(l1 - m) + __expf(l2 - m) + __expf(l3 - m));
        A.A11 = (l1 - lz) * LOG2E; A.A12 = (l2 - lz) * LOG2E; A.A13 = (l3 - lz) * LOG2E;
    }
    {
        float l2 = trans[10], l3 = trans[11];
        float m = fmaxf(l2, l3);
        float lz = m + __logf(__expf(l2 - m) + __expf(l3 - m));
        A.A22 = (l2 - lz) * LOG2E; A.A23 = (l3 - lz) * LOG2E;
    }
    A.A33 = 0.f;
    return A;
}

struct UT { float m00, m01, m02, m03, m11, m12, m13, m22, m23, m33; };

__device__ __forceinline__ void fstep(UT& M, const TransA& A, float4 e) {
    float n00 = M.m00 + A.A00 + e.x;
    float n01 = l2se2(M.m00 + A.A01, M.m01 + A.A11) + e.y;
    float n02 = l2se3(M.m00 + A.A02, M.m01 + A.A12, M.m02 + A.A22) + e.z;
    float n03 = l2se3(M.m01 + A.A13, M.m02 + A.A23, M.m03) + e.w;
    float n11 = M.m11 + A.A11 + e.y;
    float n12 = l2se2(M.m11 + A.A12, M.m12 + A.A22) + e.z;
    float n13 = l2se3(M.m11 + A.A13, M.m12 + A.A23, M.m13) + e.w;
    float n22 = M.m22 + A.A22 + e.z;
    float n23 = l2se2(M.m22 + A.A23, M.m23) + e.w;
    float n33 = M.m33 + e.w;
    M.m00 = n00; M.m01 = n01; M.m02 = n02; M.m03 = n03;
    M.m11 = n11; M.m12 = n12; M.m13 = n13; M.m22 = n22; M.m23 = n23; M.m33 = n33;
}

#define ASTEP(E) do { \
    float4 _e = (E); \
    float n0_ = a0 + A.A00; \
    float n1_ = l2se2(a0 + A.A01, a1 + A.A11); \
    float n2_ = l2se3(a0 + A.A02, a1 + A.A12, a2 + A.A22); \
    float n3_ = l2se3(a1 + A.A13, a2 + A.A23, a3); \
    a0 = n0_ + _e.x; a1 = n1_ + _e.y; a2 = n2_ + _e.z; a3 = n3_ + _e.w; \
    float mm_ = fmaxf(fmaxf(a0, a1), fmaxf(a2, a3)); \
    a0 -= mm_; a1 -= mm_; a2 -= mm_; a3 -= mm_; \
} while (0)

#define BSTEP(E) do { \
    float4 _e = (E); \
    float f0_ = _e.x + b0, f1_ = _e.y + b1, f2_ = _e.z + b2, f3_ = _e.w + b3; \
    float n0_ = l2se3(A.A00 + f0_, A.A01 + f1_, A.A02 + f2_); \
    float n1_ = l2se3(A.A11 + f1_, A.A12 + f2_, A.A13 + f3_); \
    float n2_ = l2se2(A.A22 + f2_, A.A23 + f3_); \
    float n3_ = f3_; \
    float bm_ = fmaxf(fmaxf(n0_, n1_), fmaxf(n2_, n3_)); \
    b0 = n0_ - bm_; b1 = n1_ - bm_; b2 = n2_ - bm_; b3 = n3_ - bm_; \
} while (0)

#define GEMIT(AV, Q) do { \
    float g0_ = (AV).x + b0, g1_ = (AV).y + b1, g2_ = (AV).z + b2, g3_ = (AV).w + b3; \
    float gm_ = fmaxf(fmaxf(g0_, g1_), fmaxf(g2_, g3_)); \
    float q0_ = ex2(g0_ - gm_), q1_ = ex2(g1_ - gm_); \
    float q2_ = ex2(g2_ - gm_), q3_ = ex2(g3_ - gm_); \
    float inv_ = 1.f / (q0_ + q1_ + q2_ + q3_); \
    q0_ *= inv_; q1_ *= inv_; q2_ *= inv_; q3_ *= inv_; \
    vals[(Q)*5 + 0] = fmaf(q0_, wv[0][0], fmaf(q1_, wv[1][0], fmaf(q2_, wv[2][0], q3_ * wv[3][0]))); \
    vals[(Q)*5 + 1] = fmaf(q0_, wv[0][1], fmaf(q1_, wv[1][1], fmaf(q2_, wv[2][1], q3_ * wv[3][1]))); \
    vals[(Q)*5 + 2] = fmaf(q0_, wv[0][2], fmaf(q1_, wv[1][2], fmaf(q2_, wv[2][2], q3_ * wv[3][2]))); \
    vals[(Q)*5 + 3] = fmaf(q0_, wv[0][3], fmaf(q1_, wv[1][3], fmaf(q2_, wv[2][3], q3_ * wv[3][3]))); \
    vals[(Q)*5 + 4] = fmaf(q0_, wv[0][4], fmaf(q1_, wv[1][4], fmaf(q2_, wv[2][4], q3_ * wv[3][4]))); \
} while (0)

// le in LDS, [k][c] layout (k = t&31 row, c = t>>5 col), row stride 129 float4:
// phase-1/3 readers have c per-lane -> contiguous, bank-conflict-free.
#define RDLE(T) sle[(((T) & 31) * 129) + ((T) >> 5)]

__global__ __launch_bounds__(256, 1)
void fused_kernel(const float* __restrict__ x, const float* __restrict__ emit,
                  const float* __restrict__ trans, const float* __restrict__ initl,
                  const float* __restrict__ w, float* __restrict__ out) {
    __shared__ float4 sle[32 * 129];    // 66,048 B
    __shared__ float4 uni[4352];        // 69,632 B: ops (phase1/2) aliased by alpha/beta (phase3)
    __shared__ float vinL[128 * 5];     // 2,560 B
    __shared__ float wbufL[128 * 5];    // 2,560 B
    __shared__ float Bmat[SDIM][ADIM];  // 416 B

    float4* opsF = uni;                 // 128*5 float4
    float4* opsB = uni + 640;           // 128*5 float4
    float4* abuf = uni;                 // 128*17 float4 (phase 3)
    float4* bbuf = uni + 2176;          // 128*17 float4 (phase 3)

    const int tid = threadIdx.x;
    const int bidb = blockIdx.x;

    // ---- emission distributions ----
    if (tid < SDIM) {
        float m = -1e30f;
        #pragma unroll
        for (int a = 0; a < ADIM; ++a) m = fmaxf(m, emit[tid * ADIM + a]);
        float tmp[ADIM];
        float z = 0.f;
        #pragma unroll
        for (int a = 0; a < ADIM; ++a) {
            float e = __expf(emit[tid * ADIM + a] - m);
            tmp[a] = e; z += e;
        }
        float inv = 1.f / z;
        #pragma unroll
        for (int a = 0; a < ADIM; ++a) Bmat[tid][a] = tmp[a] * inv;
    }
    __syncthreads();

    // ---- phase 0: x[bidb] -> le in LDS (2 rows / thread-iter, 16B-aligned loads) ----
    #pragma unroll 2
    for (int i = 0; i < 8; ++i) {
        int p = i * 256 + tid;                       // pair index 0..2047
        const float4* xp = reinterpret_cast<const float4*>(x) + ((size_t)bidb * 2048 + p) * 13;
        float v[52];
        #pragma unroll
        for (int q2 = 0; q2 < 13; ++q2) {
            float4 u = xp[q2];
            v[q2 * 4 + 0] = u.x; v[q2 * 4 + 1] = u.y;
            v[q2 * 4 + 2] = u.z; v[q2 * 4 + 3] = u.w;
        }
        float4 r0, r1;
        {
            float z = 0.f, d0 = 0.f, d1 = 0.f, d2 = 0.f, d3 = 0.f;
            #pragma unroll
            for (int a = 0; a < ADIM; ++a) {
                float e = ex2(v[a] * LOG2E);         // x ~ N(0,1): bounded
                z += e;
                d0 = fmaf(e, Bmat[0][a], d0); d1 = fmaf(e, Bmat[1][a], d1);
                d2 = fmaf(e, Bmat[2][a], d2); d3 = fmaf(e, Bmat[3][a], d3);
            }
            float iz = 1.f / z;
            r0.x = lg2(fmaf(d0, iz, 1e-16f)); r0.y = lg2(fmaf(d1, iz, 1e-16f));
            r0.z = lg2(fmaf(d2, iz, 1e-16f)); r0.w = lg2(fmaf(d3, iz, 1e-16f));
        }
        {
            float z = 0.f, d0 = 0.f, d1 = 0.f, d2 = 0.f, d3 = 0.f;
            #pragma unroll
            for (int a = 0; a < ADIM; ++a) {
                float e = ex2(v[26 + a] * LOG2E);
                z += e;
                d0 = fmaf(e, Bmat[0][a], d0); d1 = fmaf(e, Bmat[1][a], d1);
                d2 = fmaf(e, Bmat[2][a], d2); d3 = fmaf(e, Bmat[3][a], d3);
            }
            float iz = 1.f / z;
            r1.x = lg2(fmaf(d0, iz, 1e-16f)); r1.y = lg2(fmaf(d1, iz, 1e-16f));
            r1.z = lg2(fmaf(d2, iz, 1e-16f)); r1.w = lg2(fmaf(d3, iz, 1e-16f));
        }
        int t = p << 1;
        RDLE(t) = r0;
        RDLE(t + 1) = r1;
    }
    __syncthreads();

    TransA A = make_transA(trans);
    const int c = tid & 127;
    const int t0 = c * 32;
    const bool isB = tid >= 128;     // waves 0,1 forward; waves 2,3 backward (branch-uniform)

    // ---- phase 1: chunk operators into scan-lane layout ----
    {
        UT M;
        if (!isB) {
            float4 e0 = RDLE(t0);
            if (c == 0) {
                M.m00 = e0.x; M.m11 = e0.y; M.m22 = e0.z; M.m33 = e0.w;
                M.m01 = NEGF; M.m02 = NEGF; M.m03 = NEGF; M.m12 = NEGF; M.m13 = NEGF; M.m23 = NEGF;
            } else {
                M.m00 = A.A00 + e0.x; M.m01 = A.A01 + e0.y; M.m02 = A.A02 + e0.z; M.m03 = NEGF;
                M.m11 = A.A11 + e0.y; M.m12 = A.A12 + e0.z; M.m13 = A.A13 + e0.w;
                M.m22 = A.A22 + e0.z; M.m23 = A.A23 + e0.w; M.m33 = e0.w;
            }
            #pragma unroll
            for (int k = 1; k < 32; ++k) fstep(M, A, RDLE(t0 + k));
            opsF[c * 5 + 0] = make_float4(M.m00, NEGF,  NEGF,  NEGF );
            opsF[c * 5 + 1] = make_float4(M.m11, M.m01, NEGF,  NEGF );
            opsF[c * 5 + 2] = make_float4(M.m22, NEGF,  M.m02, M.m12);
            opsF[c * 5 + 3] = make_float4(M.m33, M.m23, M.m13, M.m03);
        } else {
            M.m00 = 0.f; M.m11 = 0.f; M.m22 = 0.f; M.m33 = 0.f;
            M.m01 = NEGF; M.m02 = NEGF; M.m03 = NEGF; M.m12 = NEGF; M.m13 = NEGF; M.m23 = NEGF;
            int jmax = (c == 127) ? (TDIM - 1) : (t0 + 32);
            #pragma unroll
            for (int k = 0; k < 32; ++k) {
                int t = t0 + 1 + k;
                if (t <= jmax) fstep(M, A, RDLE(t > TDIM - 1 ? TDIM - 1 : t));
            }
            opsB[c * 5 + 0] = make_float4(M.m00, M.m01, M.m02, M.m03);
            opsB[c * 5 + 1] = make_float4(M.m11, NEGF,  M.m13, M.m12);
            opsB[c * 5 + 2] = make_float4(M.m22, M.m23, NEGF,  NEGF );
            opsB[c * 5 + 3] = make_float4(M.m33, NEGF,  NEGF,  NEGF );
        }
    }
    __syncthreads();

    // ---- phase 2: fwd+bwd lane-parallel chunk scan (8 lanes of wave 0) ----
    if (tid < 8) {
        int j = tid & 3;
        bool bwd = tid >= 4;
        float v;
        if (!bwd) {
            float i0 = initl[0], i1 = initl[1], i2 = initl[2], i3 = initl[3];
            float m = fmaxf(fmaxf(i0, i1), fmaxf(i2, i3));
            float lz = m + __logf(__expf(i0 - m) + __expf(i1 - m) + __expf(i2 - m) + __expf(i3 - m));
            float ij = (j == 0) ? i0 : (j == 1) ? i1 : (j == 2) ? i2 : i3;
            v = (ij - lz) * LOG2E;
        } else {
            v = 0.f;
        }
        const float4* mp = bwd ? opsB : opsF;
        float* bp = bwd ? wbufL : vinL;
        for (int s = 0; s < 128; ++s) {
            int c2 = bwd ? (127 - s) : s;
            float4 mc = mp[c2 * 5 + j];
            bp[c2 * 5 + j] = v;                      // boundary BEFORE applying op
            float v1 = __shfl_xor(v, 1, 64);
            float v2 = __shfl_xor(v, 2, 64);
            float v3 = __shfl_xor(v1, 2, 64);
            float n = l2se4(v + mc.x, v1 + mc.y, v2 + mc.z, v3 + mc.w);
            float q = fmaxf(n, __shfl_xor(n, 1, 64));
            q = fmaxf(q, __shfl_xor(q, 2, 64));
            v = n - q;
        }
    }
    __syncthreads();

    // ---- phase 3: replay + gamma.w emit (fwd waves 0,1 / bwd waves 2,3) ----
    float wv[SDIM][5];
    #pragma unroll
    for (int s = 0; s < SDIM; ++s)
        #pragma unroll
        for (int o = 0; o < 5; ++o) wv[s][o] = w[s * 5 + o];

    float* opb = out + (size_t)bidb * TDIM * 5;
    float vals[20];

    if (!isB) {
        float a0 = vinL[c * 5 + 0], a1 = vinL[c * 5 + 1];
        float a2 = vinL[c * 5 + 2], a3 = vinL[c * 5 + 3];
        if (c == 0) {
            float4 e = RDLE(0);
            a0 += e.x; a1 += e.y; a2 += e.z; a3 += e.w;
            float mm = fmaxf(fmaxf(a0, a1), fmaxf(a2, a3));
            a0 -= mm; a1 -= mm; a2 -= mm; a3 -= mm;
        } else {
            ASTEP(RDLE(t0));
        }
        abuf[c * 17 + 0] = make_float4(a0, a1, a2, a3);
        #pragma unroll
        for (int k = 1; k < 16; ++k) {
            ASTEP(RDLE(t0 + k));
            abuf[c * 17 + k] = make_float4(a0, a1, a2, a3);
        }
        __syncthreads();
        float b0, b1, b2, b3;
        #pragma unroll
        for (int g = 4; g < 8; ++g) {
            #pragma unroll
            for (int q = 0; q < 4; ++q) {
                int k = g * 4 + q;
                ASTEP(RDLE(t0 + k));
                float4 bv = bbuf[c * 17 + (k - 16)];
                b0 = bv.x; b1 = bv.y; b2 = bv.z; b3 = bv.w;
                float4 av = make_float4(a0, a1, a2, a3);
                GEMIT(av, q);
            }
            float4* vo = reinterpret_cast<float4*>(opb + (size_t)(t0 + g * 4) * 5);
            vo[0] = make_float4(vals[0],  vals[1],  vals[2],  vals[3]);
            vo[1] = make_float4(vals[4],  vals[5],  vals[6],  vals[7]);
            vo[2] = make_float4(vals[8],  vals[9],  vals[10], vals[11]);
            vo[3] = make_float4(vals[12], vals[13], vals[14], vals[15]);
            vo[4] = make_float4(vals[16], vals[17], vals[18], vals[19]);
        }
    } else {
        float b0 = wbufL[c * 5 + 0], b1 = wbufL[c * 5 + 1];
        float b2 = wbufL[c * 5 + 2], b3 = wbufL[c * 5 + 3];
        bool lastc = (c == 127);
        #pragma unroll
        for (int k = 31; k >= 16; --k) {
            if (!(lastc && k == 31)) {
                int t = t0 + 1 + k;
                BSTEP(RDLE(t > TDIM - 1 ? TDIM - 1 : t));
            }
            bbuf[c * 17 + (k - 16)] = make_float4(b0, b1, b2, b3);
        }
        __syncthreads();
        #pragma unroll
        for (int g = 3; g >= 0; --g) {
            #pragma unroll
            for (int q = 3; q >= 0; --q) {
                int k = g * 4 + q;
                BSTEP(RDLE(t0 + 1 + k));
                float4 av = abuf[c * 17 + k];
                GEMIT(av, q);
            }
            float4* vo = reinterpret_cast<float4*>(opb + (size_t)(t0 + g * 4) * 5);
            vo[0] = make_float4(vals[0],  vals[1],  vals[2],  vals[3]);
            vo[1] = make_float4(vals[4],  vals[5],  vals[6],  vals[7]);
            vo[2] = make_float4(vals[8],  vals[9],  vals[10], vals[11]);
            vo[3] = make_float4(vals[12], vals[13], vals[14], vals[15]);
            vo[4] = make_float4(vals[16], vals[17], vals[18], vals[19]);
        }
    }
}

extern "C" void kernel_launch(void* const* d_in, const int* in_sizes, int n_in,
                              void* d_out, int out_size, void* d_ws, size_t ws_size,
                              hipStream_t stream) {
    const float* x     = (const float*)d_in[0];
    const float* emit  = (const float*)d_in[1];
    const float* trans = (const float*)d_in[2];
    const float* initl = (const float*)d_in[3];
    const float* w     = (const float*)d_in[4];
    float* out = (float*)d_out;

    hipLaunchKernelGGL(fused_kernel, dim3(BDIM), dim3(256), 0, stream,
                       x, emit, trans, initl, w, out);
}